// Round 8
// baseline (193.276 us; speedup 1.0000x reference)
//
#include <hip/hip_runtime.h>

// B=16, N=1024, D=512, DIRECTIONS=2
#define NB 16
#define NN 1024
#define ND 512

typedef __attribute__((ext_vector_type(8))) short short8;   // 8 x bf16
typedef __attribute__((ext_vector_type(4))) float f32x4;

typedef const __attribute__((address_space(1))) void* gptr1;
typedef __attribute__((address_space(3))) void* lptr3;

#define VMCNT0() asm volatile("s_waitcnt vmcnt(0)" ::: "memory")
#define VMCNT8() asm volatile("s_waitcnt vmcnt(8)" ::: "memory")
#define LGKM0()  asm volatile("s_waitcnt lgkmcnt(0)" ::: "memory")
#define BAR()    __builtin_amdgcn_s_barrier()

union U8 { uint4 u; short8 s; };

static __device__ __forceinline__ unsigned f2bf(float f) {
  union { float f; unsigned u; } v; v.f = f;
  unsigned r = v.u + 0x7FFFu + ((v.u >> 16) & 1u);   // RNE
  return r >> 16;
}
static __device__ __forceinline__ float bf2f(unsigned short h) {
  union { unsigned u; float f; } v; v.u = ((unsigned)h) << 16;
  return v.f;
}

// ---- k_wtcat: W [1024][512] f32 -> WTcat [1024 r][512 c] bf16 ---------------
// WTcat[dir*512 + d][c] = W[dir*512 + c][d]   (transpose within each half)
__global__ void k_wtcat(const float* __restrict__ W, unsigned short* __restrict__ WTcat) {
  __shared__ float t[64][65];
  int dir = blockIdx.z;
  int r0 = blockIdx.x * 64;   // c (W row within half)
  int c0 = blockIdx.y * 64;   // d
  int tid = threadIdx.x;
#pragma unroll
  for (int i = 0; i < 4; ++i) {
    int f = i * 256 + tid;
    int r = f >> 4, cq = f & 15;
    float4 v = *(const float4*)(W + (size_t)(dir * 512 + r0 + r) * ND + c0 + cq * 4);
    t[r][cq * 4 + 0] = v.x; t[r][cq * 4 + 1] = v.y;
    t[r][cq * 4 + 2] = v.z; t[r][cq * 4 + 3] = v.w;
  }
  __syncthreads();
#pragma unroll
  for (int i = 0; i < 8; ++i) {
    int f = i * 256 + tid;
    int oc = f >> 5;            // d-local
    int on = (f & 31) * 2;      // c-local pair
    unsigned lo = f2bf(t[on][oc]), hi = f2bf(t[on + 1][oc]);
    *(unsigned*)(WTcat + (size_t)(dir * 512 + c0 + oc) * ND + r0 + on) = lo | (hi << 16);
  }
}

// ---- k_pack: adj int32 -> 2-bit codes (bit0: ==1, bit1: ==2) + inv counts ---
__global__ void k_pack(const int* __restrict__ adj, unsigned* __restrict__ packed,
                       float* __restrict__ invc) {
  int wid = threadIdx.x >> 6, lane = threadIdx.x & 63;
  int wrow0 = (blockIdx.x * 4 + wid) * 4;
#pragma unroll
  for (int r = 0; r < 4; ++r) {
    int row = wrow0 + r;
    const int* p = adj + (size_t)row * NN + lane * 16;
    unsigned u = 0;
#pragma unroll
    for (int i = 0; i < 4; ++i) {
      int4 v = *(const int4*)(p + i * 4);
      u |= ((unsigned)v.x << (8 * i)) | ((unsigned)v.y << (8 * i + 2))
         | ((unsigned)v.z << (8 * i + 4)) | ((unsigned)v.w << (8 * i + 6));
    }
    packed[(size_t)row * 64 + lane] = u;
    unsigned c1 = __popc(u & 0x55555555u);
    unsigned c2 = __popc(u & 0xAAAAAAAAu);
    unsigned pr = c1 | (c2 << 16);
#pragma unroll
    for (int o = 32; o; o >>= 1) pr += __shfl_xor(pr, o);
    if (lane == 0) {
      invc[row * 2 + 0] = 1.0f / ((float)(pr & 0xFFFFu) + 1e-13f);
      invc[row * 2 + 1] = 1.0f / ((float)(pr >> 16) + 1e-13f);
    }
  }
}

// ---- k_pre: Ptcat[b][r][m] = bf16( sum_c WTcat[r][c] * hid[b][m][c] ) -------
// One GEMM: M=1024 (r), N=1024 (m), K=512 (c). BM=BN=128, BK=64. Single acc.
__global__ __launch_bounds__(256, 2) void k_pre(
    const float* __restrict__ hid, const unsigned short* __restrict__ WTcat,
    unsigned short* __restrict__ Ptcat) {
  __shared__ __align__(16) char smem[49152];   // A dbuf 2x16KB @0; Bh 16KB @32768
  char* Bh = smem + 32768;

  int phys = blockIdx.x;                       // 1024 blocks
  int logical = (phys & 7) * 128 + (phys >> 3);
  int b = logical >> 6;
  int rem = logical & 63;
  int rt = rem >> 3, mt = rem & 7;
  int r0 = rt * 128, m0 = mt * 128;

  int tid = threadIdx.x, lane = tid & 63, wid = tid >> 6;
  int wr = wid >> 1, wc = wid & 1;
  int l15 = lane & 15, lq = lane >> 4;
  int srow = lane >> 3;
  int ssl = (lane & 7) ^ srow;

  const float* hb = hid + (size_t)b * NN * ND;

  f32x4 acc[4][4];
  f32x4 zero = {0.f, 0.f, 0.f, 0.f};
#pragma unroll
  for (int i = 0; i < 4; ++i)
#pragma unroll
    for (int j = 0; j < 4; ++j) acc[i][j] = zero;

  float4 fc[8], fn[8];
#pragma unroll
  for (int it = 0; it < 8; ++it) {
    int f = it * 256 + tid;
    fc[it] = *(const float4*)(hb + (size_t)(m0 + (f >> 4)) * ND + (f & 15) * 4);
  }
#pragma unroll
  for (int i = 0; i < 4; ++i) {
    int q = wid * 4 + i;
    int r = q * 8 + srow;
    __builtin_amdgcn_global_load_lds((gptr1)(WTcat + (size_t)(r0 + r) * ND + ssl * 8),
                                     (lptr3)(smem + q * 1024), 16, 0, 0);
  }

#pragma unroll 1
  for (int kt = 0; kt < 8; ++kt) {
    int k0 = kt * 64;
    // convert fc -> Bh ([128 m][64 c] bf16, swizzled)
#pragma unroll
    for (int it = 0; it < 8; ++it) {
      int f = it * 256 + tid;
      int row = f >> 4, c4 = f & 15;
      float4 v = fc[it];
      unsigned lo = f2bf(v.x) | (f2bf(v.y) << 16);
      unsigned hi = f2bf(v.z) | (f2bf(v.w) << 16);
      int addr = row * 128 + (((c4 >> 1) ^ (row & 7)) * 16) + (c4 & 1) * 8;
      *(uint2*)(Bh + addr) = make_uint2(lo, hi);
    }
    if (kt < 7) {
#pragma unroll
      for (int it = 0; it < 8; ++it) {
        int f = it * 256 + tid;
        fn[it] = *(const float4*)(hb + (size_t)(m0 + (f >> 4)) * ND + k0 + 64 + (f & 15) * 4);
      }
      VMCNT8();                 // drain A-DMA(kt), keep fn in flight
    } else {
      VMCNT0();
    }
    LGKM0();
    BAR();
    if (kt < 7) {
      char* ab = smem + (((kt + 1) & 1) << 14);
#pragma unroll
      for (int i = 0; i < 4; ++i) {
        int q = wid * 4 + i;
        int r = q * 8 + srow;
        __builtin_amdgcn_global_load_lds((gptr1)(WTcat + (size_t)(r0 + r) * ND + k0 + 64 + ssl * 8),
                                         (lptr3)(ab + q * 1024), 16, 0, 0);
      }
    }
    const char* ac = smem + ((kt & 1) << 14);
    __builtin_amdgcn_s_setprio(1);
#pragma unroll
    for (int ks = 0; ks < 2; ++ks) {
      short8 a[4], bf[4];
#pragma unroll
      for (int mi = 0; mi < 4; ++mi) {
        int row = wr * 64 + mi * 16 + l15;
        int slot = (ks * 4 + lq) ^ (l15 & 7);
        a[mi] = *(const short8*)(ac + row * 128 + slot * 16);
      }
#pragma unroll
      for (int nj = 0; nj < 4; ++nj) {
        int col = wc * 64 + nj * 16 + l15;
        int slot = (ks * 4 + lq) ^ (l15 & 7);
        bf[nj] = *(const short8*)(Bh + col * 128 + slot * 16);
      }
#pragma unroll
      for (int mi = 0; mi < 4; ++mi)
#pragma unroll
        for (int nj = 0; nj < 4; ++nj)
          acc[mi][nj] = __builtin_amdgcn_mfma_f32_16x16x32_bf16(a[mi], bf[nj], acc[mi][nj], 0, 0, 0);
    }
    __builtin_amdgcn_s_setprio(0);
    BAR();
    if (kt < 7) {
#pragma unroll
      for (int it = 0; it < 8; ++it) fc[it] = fn[it];
    }
    __builtin_amdgcn_sched_barrier(0);
  }
  unsigned short* Pb = Ptcat + (size_t)b * NN * NN;
#pragma unroll
  for (int mi = 0; mi < 4; ++mi) {
#pragma unroll
    for (int rr = 0; rr < 4; ++rr) {
      int r = r0 + wr * 64 + mi * 16 + lq * 4 + rr;
#pragma unroll
      for (int nj = 0; nj < 4; ++nj) {
        int m = m0 + wc * 64 + nj * 16 + l15;
        Pb[(size_t)r * NN + m] = (unsigned short)f2bf(acc[mi][nj][rr]);
      }
    }
  }
}

// ---- k_main: preS[n][d] = bf16(relu(i1*S1 + i2*S2 + bias) + hid) ------------
// Dir-major K'=2048, one dir per kt; accA (kt<16) / accB (kt>=16); weights f32
// in epilogue. A = {0,1} mask frags unpacked per-lane in regs (no LDS);
// B = Ptcat tile [128 d][64 m] DMA-dbuf in LDS; 1 barrier + vmcnt(8) per kt.
__global__ __launch_bounds__(256, 2) void k_main(
    const unsigned* __restrict__ packed, const unsigned short* __restrict__ Ptcat,
    const float* __restrict__ invc, const float* __restrict__ bias,
    const float* __restrict__ hid, unsigned short* __restrict__ preS) {
  __shared__ __align__(16) char smB[32768];    // B dbuf 2 x [128][64] bf16

  int phys = blockIdx.x;                       // 512 blocks
  int logical = (phys & 7) * 64 + (phys >> 3);
  int b = logical >> 5;
  int rem = logical & 31;
  int mt = rem >> 2, dt = rem & 3;
  int n0 = mt * 128, d0 = dt * 128;

  int tid = threadIdx.x, lane = tid & 63, wid = tid >> 6;
  int wr = wid >> 1, wc = wid & 1;
  int l15 = lane & 15, lq = lane >> 4;
  int srow = lane >> 3;
  int ssl = (lane & 7) ^ srow;
  size_t bN = (size_t)b * NN;

  const unsigned* cp[4];
#pragma unroll
  for (int mi = 0; mi < 4; ++mi)
    cp[mi] = packed + (bN + n0 + wr * 64 + mi * 16 + l15) * 64 + (lq >> 1);

  const unsigned short* Ptb = Ptcat + bN * NN;   // [1024 r][1024 m]

  const char* base0 = smB + (wc * 64 + l15) * 128 + ((lq ^ (l15 & 7)) * 16);
  const char* base1 = smB + (wc * 64 + l15) * 128 + (((4 + lq) ^ (l15 & 7)) * 16);

  f32x4 accA[4][4], accB[4][4];
  f32x4 zero = {0.f, 0.f, 0.f, 0.f};
#pragma unroll
  for (int i = 0; i < 4; ++i)
#pragma unroll
    for (int j = 0; j < 4; ++j) { accA[i][j] = zero; accB[i][j] = zero; }

  // prologue: B-DMA(0) (dir0, k0=0), codes(0)
#pragma unroll
  for (int i = 0; i < 4; ++i) {
    int q = wid * 4 + i;
    __builtin_amdgcn_global_load_lds((gptr1)(Ptb + (size_t)(d0 + q * 8 + srow) * NN + ssl * 8),
                                     (lptr3)(smB + q * 1024), 16, 0, 0);
  }
  unsigned cc[8], cn[8];
#pragma unroll
  for (int mi = 0; mi < 4; ++mi) { cc[mi * 2] = cp[mi][0]; cc[mi * 2 + 1] = cp[mi][2]; }

  unsigned tgl = 0;
#pragma unroll 1
  for (int kt = 0; kt < 32; ++kt) {
    VMCNT8();                    // B-DMA(kt) landed (code loads may remain)
    BAR();
    if (kt < 31) {
      int t = kt + 1;
      int dirn = t >> 4;
      int k0n = (t & 15) * 64;
#pragma unroll
      for (int i = 0; i < 4; ++i) {
        int q = wid * 4 + i;
        __builtin_amdgcn_global_load_lds(
            (gptr1)(Ptb + (size_t)(dirn * 512 + d0 + q * 8 + srow) * NN + k0n + ssl * 8),
            (lptr3)(smB + (tgl ^ 16384) + q * 1024), 16, 0, 0);
      }
      int cw = (t & 15) * 4;     // FIX: codes are dir-independent (bit selects dir)
#pragma unroll
      for (int mi = 0; mi < 4; ++mi) {
        cn[mi * 2]     = cp[mi][cw];
        cn[mi * 2 + 1] = cp[mi][cw + 2];
      }
    }
    int dir = kt >> 4;
    unsigned shb = (unsigned)((lq & 1) * 16 + dir);
#pragma unroll
    for (int ks = 0; ks < 2; ++ks) {
      short8 bf[4];
      const char* bs = (ks == 0) ? base0 : base1;
#pragma unroll
      for (int nj = 0; nj < 4; ++nj)
        bf[nj] = *(const short8*)(bs + tgl + nj * 2048);
      U8 a[4];
#pragma unroll
      for (int mi = 0; mi < 4; ++mi) {
        unsigned cd = cc[mi * 2 + ks] >> shb;
#pragma unroll
        for (int j = 0; j < 4; ++j) {
          unsigned t5 = (cd >> (4 * j)) & 5u;
          a[mi].u[j] = ((t5 | (t5 << 14)) & 0x00010001u) * 0x3F80u;
        }
      }
      __builtin_amdgcn_s_setprio(1);
      if (kt < 16) {
#pragma unroll
        for (int nj = 0; nj < 4; ++nj)
#pragma unroll
          for (int mi = 0; mi < 4; ++mi)
            accA[mi][nj] = __builtin_amdgcn_mfma_f32_16x16x32_bf16(a[mi].s, bf[nj], accA[mi][nj], 0, 0, 0);
      } else {
#pragma unroll
        for (int nj = 0; nj < 4; ++nj)
#pragma unroll
          for (int mi = 0; mi < 4; ++mi)
            accB[mi][nj] = __builtin_amdgcn_mfma_f32_16x16x32_bf16(a[mi].s, bf[nj], accB[mi][nj], 0, 0, 0);
      }
      __builtin_amdgcn_s_setprio(0);
    }
    if (kt < 31) {
#pragma unroll
      for (int i = 0; i < 8; ++i) cc[i] = cn[i];
    }
    tgl ^= 16384;
  }

  // epilogue: f32 weights, bias, relu, residual; write pre-LN bf16
#pragma unroll
  for (int mi = 0; mi < 4; ++mi) {
#pragma unroll
    for (int rr = 0; rr < 4; ++rr) {
      int n = n0 + wr * 64 + mi * 16 + lq * 4 + rr;
      float i1 = invc[(bN + n) * 2 + 0];
      float i2 = invc[(bN + n) * 2 + 1];
      const float* hrow = hid + (bN + n) * ND;
      unsigned short* prow = preS + (bN + n) * ND;
#pragma unroll
      for (int nj = 0; nj < 4; ++nj) {
        int d = d0 + wc * 64 + nj * 16 + l15;
        float v = accA[mi][nj][rr] * i1 + accB[mi][nj][rr] * i2 + bias[d];
        v = fmaxf(v, 0.f);
        v += hrow[d];
        prow[d] = (unsigned short)f2bf(v);
      }
    }
  }
}

// ---- k_ln: rowwise LayerNorm, bf16 preS -> f32 out --------------------------
__global__ void k_ln(const unsigned short* __restrict__ preS, float* __restrict__ out,
                     const float* __restrict__ gamma, const float* __restrict__ beta) {
  int row = blockIdx.x * 4 + (threadIdx.x >> 6);
  int lane = threadIdx.x & 63;
  short8 raw = *(const short8*)(preS + (size_t)row * ND + lane * 8);
  float x[8];
#pragma unroll
  for (int i = 0; i < 8; ++i) x[i] = bf2f((unsigned short)raw[i]);
  float s = 0.f;
#pragma unroll
  for (int i = 0; i < 8; ++i) s += x[i];
#pragma unroll
  for (int o = 32; o; o >>= 1) s += __shfl_xor(s, o);
  float mu = s * (1.0f / 512.0f);
  float v = 0.f;
#pragma unroll
  for (int i = 0; i < 8; ++i) { float d = x[i] - mu; v += d * d; }
#pragma unroll
  for (int o = 32; o; o >>= 1) v += __shfl_xor(v, o);
  float rs = rsqrtf(v * (1.0f / 512.0f) + 1e-5f);
  float4 g0 = *(const float4*)(gamma + lane * 8);
  float4 g1 = *(const float4*)(gamma + lane * 8 + 4);
  float4 b0 = *(const float4*)(beta + lane * 8);
  float4 b1 = *(const float4*)(beta + lane * 8 + 4);
  float4 y0, y1;
  y0.x = (x[0] - mu) * rs * g0.x + b0.x; y0.y = (x[1] - mu) * rs * g0.y + b0.y;
  y0.z = (x[2] - mu) * rs * g0.z + b0.z; y0.w = (x[3] - mu) * rs * g0.w + b0.w;
  y1.x = (x[4] - mu) * rs * g1.x + b1.x; y1.y = (x[5] - mu) * rs * g1.y + b1.y;
  y1.z = (x[6] - mu) * rs * g1.z + b1.z; y1.w = (x[7] - mu) * rs * g1.w + b1.w;
  float* p = out + (size_t)row * ND + lane * 8;
  *(float4*)p = y0;
  *(float4*)(p + 4) = y1;
}

extern "C" void kernel_launch(void* const* d_in, const int* in_sizes, int n_in,
                              void* d_out, int out_size, void* d_ws, size_t ws_size,
                              hipStream_t stream) {
  (void)in_sizes; (void)n_in; (void)out_size; (void)ws_size;
  const int*   adj   = (const int*)d_in[0];
  const float* hid   = (const float*)d_in[1];
  const float* W     = (const float*)d_in[2];
  const float* bias  = (const float*)d_in[3];
  const float* gamma = (const float*)d_in[4];
  const float* beta  = (const float*)d_in[5];
  float* out = (float*)d_out;

  char* ws = (char*)d_ws;
  // Overlapping lifetimes: WTcat (1 MiB, dead after k_pre) shares offset 0
  // with preS (16 MiB, written by k_main afterwards).
  unsigned short* WTcat  = (unsigned short*)ws;                 // 1 MiB
  unsigned short* preS   = (unsigned short*)ws;                 // 16 MiB (after k_pre)
  unsigned short* Ptcat  = (unsigned short*)(ws + 16777216);    // 32 MiB
  unsigned*       packed = (unsigned*)(ws + 50331648);          // 4 MiB
  float*          invc   = (float*)(ws + 54525952);             // 128 KiB

  k_wtcat<<<dim3(8, 8, 2), 256, 0, stream>>>(W, WTcat);
  k_pack <<<1024, 256, 0, stream>>>(adj, packed, invc);
  k_pre  <<<1024, 256, 0, stream>>>(hid, WTcat, Ptcat);
  k_main <<<512, 256, 0, stream>>>(packed, Ptcat, invc, bias, hid, preS);
  k_ln   <<<4096, 256, 0, stream>>>(preS, out, gamma, beta);
}

// Round 9
// 112.913 us; speedup vs baseline: 1.7117x; 1.7117x over previous
//
#include <hip/hip_runtime.h>

// B=16, N=1024, D=512, DIRECTIONS=2
#define NB 16
#define NN 1024
#define ND 512

typedef __attribute__((ext_vector_type(8))) short short8;   // 8 x bf16
typedef __attribute__((ext_vector_type(4))) float f32x4;

typedef const __attribute__((address_space(1))) void* gptr1;
typedef __attribute__((address_space(3))) void* lptr3;

#define VMCNT0() asm volatile("s_waitcnt vmcnt(0)" ::: "memory")
#define VMCNT4() asm volatile("s_waitcnt vmcnt(4)" ::: "memory")
#define VMCNT8() asm volatile("s_waitcnt vmcnt(8)" ::: "memory")
#define LGKM0()  asm volatile("s_waitcnt lgkmcnt(0)" ::: "memory")
#define BAR()    __builtin_amdgcn_s_barrier()

union U8 { uint4 u; short8 s; };

static __device__ __forceinline__ unsigned f2bf(float f) {
  union { float f; unsigned u; } v; v.f = f;
  unsigned r = v.u + 0x7FFFu + ((v.u >> 16) & 1u);   // RNE
  return r >> 16;
}
static __device__ __forceinline__ float bf2f(unsigned short h) {
  union { unsigned u; float f; } v; v.u = ((unsigned)h) << 16;
  return v.f;
}

// ---- k_wtcat: W [1024][512] f32 -> WTcat [1024 r][512 c] bf16 ---------------
__global__ void k_wtcat(const float* __restrict__ W, unsigned short* __restrict__ WTcat) {
  __shared__ float t[64][65];
  int dir = blockIdx.z;
  int r0 = blockIdx.x * 64;   // c (W row within half)
  int c0 = blockIdx.y * 64;   // d
  int tid = threadIdx.x;
#pragma unroll
  for (int i = 0; i < 4; ++i) {
    int f = i * 256 + tid;
    int r = f >> 4, cq = f & 15;
    float4 v = *(const float4*)(W + (size_t)(dir * 512 + r0 + r) * ND + c0 + cq * 4);
    t[r][cq * 4 + 0] = v.x; t[r][cq * 4 + 1] = v.y;
    t[r][cq * 4 + 2] = v.z; t[r][cq * 4 + 3] = v.w;
  }
  __syncthreads();
#pragma unroll
  for (int i = 0; i < 8; ++i) {
    int f = i * 256 + tid;
    int oc = f >> 5;            // d-local
    int on = (f & 31) * 2;      // c-local pair
    unsigned lo = f2bf(t[on][oc]), hi = f2bf(t[on + 1][oc]);
    *(unsigned*)(WTcat + (size_t)(dir * 512 + c0 + oc) * ND + r0 + on) = lo | (hi << 16);
  }
}

// ---- k_pack: adj -> 2-bit codes, PERMUTED word order [w0,w2,w1,w3] per group,
//      so a lane's (ks0,ks1) words are one aligned uint2. Also inv counts.
__global__ void k_pack(const int* __restrict__ adj, unsigned* __restrict__ packed,
                       float* __restrict__ invc) {
  int wid = threadIdx.x >> 6, lane = threadIdx.x & 63;
  int wrow0 = (blockIdx.x * 4 + wid) * 4;
  int pl = (lane & ~3) | ((lane & 1) << 1) | ((lane >> 1) & 1);   // perm position
#pragma unroll
  for (int r = 0; r < 4; ++r) {
    int row = wrow0 + r;
    const int* p = adj + (size_t)row * NN + lane * 16;
    unsigned u = 0;
#pragma unroll
    for (int i = 0; i < 4; ++i) {
      int4 v = *(const int4*)(p + i * 4);
      u |= ((unsigned)v.x << (8 * i)) | ((unsigned)v.y << (8 * i + 2))
         | ((unsigned)v.z << (8 * i + 4)) | ((unsigned)v.w << (8 * i + 6));
    }
    packed[(size_t)row * 64 + pl] = u;
    unsigned c1 = __popc(u & 0x55555555u);
    unsigned c2 = __popc(u & 0xAAAAAAAAu);
    unsigned pr = c1 | (c2 << 16);
#pragma unroll
    for (int o = 32; o; o >>= 1) pr += __shfl_xor(pr, o);
    if (lane == 0) {
      invc[row * 2 + 0] = 1.0f / ((float)(pr & 0xFFFFu) + 1e-13f);
      invc[row * 2 + 1] = 1.0f / ((float)(pr >> 16) + 1e-13f);
    }
  }
}

// ---- k_pre: Ptcat[b][r][m] = bf16( sum_c WTcat[r][c] * hid[b][m][c] ) -------
// One GEMM: M=1024 (r), N=1024 (m), K=512 (c). BM=BN=128, BK=64. Single acc.
__global__ __launch_bounds__(256, 2) void k_pre(
    const float* __restrict__ hid, const unsigned short* __restrict__ WTcat,
    unsigned short* __restrict__ Ptcat) {
  __shared__ __align__(16) char smem[49152];   // A dbuf 2x16KB @0; Bh 16KB @32768
  char* Bh = smem + 32768;

  int phys = blockIdx.x;                       // 1024 blocks
  int logical = (phys & 7) * 128 + (phys >> 3);
  int b = logical >> 6;
  int rem = logical & 63;
  int rt = rem >> 3, mt = rem & 7;
  int r0 = rt * 128, m0 = mt * 128;

  int tid = threadIdx.x, lane = tid & 63, wid = tid >> 6;
  int wr = wid >> 1, wc = wid & 1;
  int l15 = lane & 15, lq = lane >> 4;
  int srow = lane >> 3;
  int ssl = (lane & 7) ^ srow;

  const float* hb = hid + (size_t)b * NN * ND;

  f32x4 acc[4][4];
  f32x4 zero = {0.f, 0.f, 0.f, 0.f};
#pragma unroll
  for (int i = 0; i < 4; ++i)
#pragma unroll
    for (int j = 0; j < 4; ++j) acc[i][j] = zero;

  float4 fc[8], fn[8];
#pragma unroll
  for (int it = 0; it < 8; ++it) {
    int f = it * 256 + tid;
    fc[it] = *(const float4*)(hb + (size_t)(m0 + (f >> 4)) * ND + (f & 15) * 4);
  }
#pragma unroll
  for (int i = 0; i < 4; ++i) {
    int q = wid * 4 + i;
    int r = q * 8 + srow;
    __builtin_amdgcn_global_load_lds((gptr1)(WTcat + (size_t)(r0 + r) * ND + ssl * 8),
                                     (lptr3)(smem + q * 1024), 16, 0, 0);
  }

#pragma unroll 1
  for (int kt = 0; kt < 8; ++kt) {
    int k0 = kt * 64;
    // convert fc -> Bh ([128 m][64 c] bf16, swizzled)
#pragma unroll
    for (int it = 0; it < 8; ++it) {
      int f = it * 256 + tid;
      int row = f >> 4, c4 = f & 15;
      float4 v = fc[it];
      unsigned lo = f2bf(v.x) | (f2bf(v.y) << 16);
      unsigned hi = f2bf(v.z) | (f2bf(v.w) << 16);
      int addr = row * 128 + (((c4 >> 1) ^ (row & 7)) * 16) + (c4 & 1) * 8;
      *(uint2*)(Bh + addr) = make_uint2(lo, hi);
    }
    if (kt < 7) {
#pragma unroll
      for (int it = 0; it < 8; ++it) {
        int f = it * 256 + tid;
        fn[it] = *(const float4*)(hb + (size_t)(m0 + (f >> 4)) * ND + k0 + 64 + (f & 15) * 4);
      }
      VMCNT8();                 // drain A-DMA(kt), keep fn in flight
    } else {
      VMCNT0();
    }
    LGKM0();
    BAR();
    if (kt < 7) {
      char* ab = smem + (((kt + 1) & 1) << 14);
#pragma unroll
      for (int i = 0; i < 4; ++i) {
        int q = wid * 4 + i;
        int r = q * 8 + srow;
        __builtin_amdgcn_global_load_lds((gptr1)(WTcat + (size_t)(r0 + r) * ND + k0 + 64 + ssl * 8),
                                         (lptr3)(ab + q * 1024), 16, 0, 0);
      }
    }
    const char* ac = smem + ((kt & 1) << 14);
    __builtin_amdgcn_s_setprio(1);
#pragma unroll
    for (int ks = 0; ks < 2; ++ks) {
      short8 a[4], bf[4];
#pragma unroll
      for (int mi = 0; mi < 4; ++mi) {
        int row = wr * 64 + mi * 16 + l15;
        int slot = (ks * 4 + lq) ^ (l15 & 7);
        a[mi] = *(const short8*)(ac + row * 128 + slot * 16);
      }
#pragma unroll
      for (int nj = 0; nj < 4; ++nj) {
        int col = wc * 64 + nj * 16 + l15;
        int slot = (ks * 4 + lq) ^ (l15 & 7);
        bf[nj] = *(const short8*)(Bh + col * 128 + slot * 16);
      }
#pragma unroll
      for (int mi = 0; mi < 4; ++mi)
#pragma unroll
        for (int nj = 0; nj < 4; ++nj)
          acc[mi][nj] = __builtin_amdgcn_mfma_f32_16x16x32_bf16(a[mi], bf[nj], acc[mi][nj], 0, 0, 0);
    }
    __builtin_amdgcn_s_setprio(0);
    BAR();
    if (kt < 7) {
#pragma unroll
      for (int it = 0; it < 8; ++it) fc[it] = fn[it];
    }
    __builtin_amdgcn_sched_barrier(0);
  }
  unsigned short* Pb = Ptcat + (size_t)b * NN * NN;
#pragma unroll
  for (int mi = 0; mi < 4; ++mi) {
#pragma unroll
    for (int rr = 0; rr < 4; ++rr) {
      int r = r0 + wr * 64 + mi * 16 + lq * 4 + rr;
#pragma unroll
      for (int nj = 0; nj < 4; ++nj) {
        int m = m0 + wc * 64 + nj * 16 + l15;
        Pb[(size_t)r * NN + m] = (unsigned short)f2bf(acc[mi][nj][rr]);
      }
    }
  }
}

// ---- k_main: preS[n][d] = bf16(relu(i1*S1 + i2*S2 + bias) + hid) ------------
// Dir-major K'=2048; A-masks unpacked per-lane in regs from 2-ahead-prefetched
// codes (ping-pong reg sets, no copies); B = Ptcat DMA-dbuf in LDS.
// Per kt: vmcnt(4) drains exactly {codes(kt), DMA(kt)}, keeps codes(kt+1).
__global__ __launch_bounds__(256, 2) void k_main(
    const unsigned* __restrict__ packed, const unsigned short* __restrict__ Ptcat,
    const float* __restrict__ invc, const float* __restrict__ bias,
    const float* __restrict__ hid, unsigned short* __restrict__ preS) {
  __shared__ __align__(16) char smB[32768];    // B dbuf 2 x [128 d][64 m] bf16

  int phys = blockIdx.x;                       // 512 blocks
  int logical = (phys & 7) * 64 + (phys >> 3);
  int b = logical >> 5;
  int rem = logical & 31;
  int mt = rem >> 2, dt = rem & 3;
  int n0 = mt * 128, d0 = dt * 128;

  int tid = threadIdx.x, lane = tid & 63, wid = tid >> 6;
  int wr = wid >> 1, wc = wid & 1;
  int l15 = lane & 15, lq = lane >> 4;
  int h2 = lq >> 1;
  int srow = lane >> 3;
  int ssl = (lane & 7) ^ srow;
  size_t bN = (size_t)b * NN;

  const unsigned* cbase[4];
#pragma unroll
  for (int mi = 0; mi < 4; ++mi)
    cbase[mi] = packed + (bN + n0 + wr * 64 + mi * 16 + l15) * 64 + 2 * h2;

  const unsigned short* Ptb = Ptcat + bN * NN;   // [1024 r][1024 m]

  const char* base0 = smB + (wc * 64 + l15) * 128 + ((lq ^ (l15 & 7)) * 16);
  const char* base1 = smB + (wc * 64 + l15) * 128 + (((4 + lq) ^ (l15 & 7)) * 16);

  f32x4 accA[4][4], accB[4][4];
  f32x4 zero = {0.f, 0.f, 0.f, 0.f};
#pragma unroll
  for (int i = 0; i < 4; ++i)
#pragma unroll
    for (int j = 0; j < 4; ++j) { accA[i][j] = zero; accB[i][j] = zero; }

  // prologue: codes(0) -> cA, DMA(0) -> buf0, codes(1) -> cB   (12 outstanding)
  uint2 cA[4], cB[4];
#pragma unroll
  for (int mi = 0; mi < 4; ++mi) cA[mi] = *(const uint2*)(cbase[mi]);
#pragma unroll
  for (int i = 0; i < 4; ++i) {
    int q = wid * 4 + i;
    __builtin_amdgcn_global_load_lds((gptr1)(Ptb + (size_t)(d0 + q * 8 + srow) * NN + ssl * 8),
                                     (lptr3)(smB + q * 1024), 16, 0, 0);
  }
#pragma unroll
  for (int mi = 0; mi < 4; ++mi) cB[mi] = *(const uint2*)(cbase[mi] + 4);

  unsigned shb = (unsigned)((lq & 1) * 16);    // + dir, set per dir-loop

// One kt step. CSET = code reg set for this kt (reloaded for kt+2 after use).
#define KT_BODY(KT_, CSET, ACC)                                               \
  {                                                                           \
    int kt = (KT_);                                                           \
    if (kt == 31) { VMCNT0(); } else { VMCNT4(); }                            \
    BAR();                                                                    \
    if (kt < 31) {                                                            \
      int t = kt + 1; int dirn = t >> 4; int k0n = (t & 15) * 64;             \
      _Pragma("unroll")                                                       \
      for (int i = 0; i < 4; ++i) {                                           \
        int q = wid * 4 + i;                                                  \
        __builtin_amdgcn_global_load_lds(                                     \
          (gptr1)(Ptb + (size_t)(dirn * 512 + d0 + q * 8 + srow) * NN + k0n + ssl * 8), \
          (lptr3)(smB + ((~kt & 1) << 14) + q * 1024), 16, 0, 0);             \
      }                                                                       \
    }                                                                         \
    const char* bb0 = base0 + ((kt & 1) << 14);                               \
    const char* bb1 = base1 + ((kt & 1) << 14);                               \
    short8 bf0[4], bf1[4];                                                    \
    _Pragma("unroll")                                                         \
    for (int nj = 0; nj < 4; ++nj) {                                          \
      bf0[nj] = *(const short8*)(bb0 + nj * 2048);                            \
      bf1[nj] = *(const short8*)(bb1 + nj * 2048);                            \
    }                                                                         \
    U8 a0[4], a1[4];                                                          \
    _Pragma("unroll")                                                         \
    for (int mi = 0; mi < 4; ++mi) {                                          \
      unsigned cd0 = CSET[mi].x >> shb;                                       \
      unsigned cd1 = CSET[mi].y >> shb;                                       \
      _Pragma("unroll")                                                       \
      for (int j = 0; j < 4; ++j) {                                           \
        unsigned t5 = (cd0 >> (4 * j)) & 5u;                                  \
        a0[mi].u[j] = ((t5 | (t5 << 14)) & 0x00010001u) * 0x3F80u;            \
        unsigned s5 = (cd1 >> (4 * j)) & 5u;                                  \
        a1[mi].u[j] = ((s5 | (s5 << 14)) & 0x00010001u) * 0x3F80u;            \
      }                                                                       \
    }                                                                         \
    __builtin_amdgcn_s_setprio(1);                                            \
    _Pragma("unroll")                                                         \
    for (int nj = 0; nj < 4; ++nj)                                            \
      _Pragma("unroll")                                                       \
      for (int mi = 0; mi < 4; ++mi)                                          \
        ACC[mi][nj] = __builtin_amdgcn_mfma_f32_16x16x32_bf16(a0[mi].s, bf0[nj], ACC[mi][nj], 0, 0, 0); \
    _Pragma("unroll")                                                         \
    for (int nj = 0; nj < 4; ++nj)                                            \
      _Pragma("unroll")                                                       \
      for (int mi = 0; mi < 4; ++mi)                                          \
        ACC[mi][nj] = __builtin_amdgcn_mfma_f32_16x16x32_bf16(a1[mi].s, bf1[nj], ACC[mi][nj], 0, 0, 0); \
    __builtin_amdgcn_s_setprio(0);                                            \
    if (kt < 30) {                                                            \
      int g2 = (kt + 2) & 15;                                                 \
      _Pragma("unroll")                                                       \
      for (int mi = 0; mi < 4; ++mi)                                          \
        CSET[mi] = *(const uint2*)(cbase[mi] + g2 * 4);                       \
    }                                                                         \
  }

#pragma unroll 1
  for (int kk = 0; kk < 8; ++kk) {       // dir 0: kt 0..15
    KT_BODY(kk * 2,     cA, accA)
    KT_BODY(kk * 2 + 1, cB, accA)
  }
  shb = (unsigned)((lq & 1) * 16 + 1);
#pragma unroll 1
  for (int kk = 8; kk < 16; ++kk) {      // dir 1: kt 16..31
    KT_BODY(kk * 2,     cA, accB)
    KT_BODY(kk * 2 + 1, cB, accB)
  }
#undef KT_BODY

  // epilogue: f32 weights, bias, relu, residual; write pre-LN bf16
#pragma unroll
  for (int mi = 0; mi < 4; ++mi) {
#pragma unroll
    for (int rr = 0; rr < 4; ++rr) {
      int n = n0 + wr * 64 + mi * 16 + lq * 4 + rr;
      float i1 = invc[(bN + n) * 2 + 0];
      float i2 = invc[(bN + n) * 2 + 1];
      const float* hrow = hid + (bN + n) * ND;
      unsigned short* prow = preS + (bN + n) * ND;
#pragma unroll
      for (int nj = 0; nj < 4; ++nj) {
        int d = d0 + wc * 64 + nj * 16 + l15;
        float v = accA[mi][nj][rr] * i1 + accB[mi][nj][rr] * i2 + bias[d];
        v = fmaxf(v, 0.f);
        v += hrow[d];
        prow[d] = (unsigned short)f2bf(v);
      }
    }
  }
}

// ---- k_ln: rowwise LayerNorm, bf16 preS -> f32 out --------------------------
__global__ void k_ln(const unsigned short* __restrict__ preS, float* __restrict__ out,
                     const float* __restrict__ gamma, const float* __restrict__ beta) {
  int row = blockIdx.x * 4 + (threadIdx.x >> 6);
  int lane = threadIdx.x & 63;
  short8 raw = *(const short8*)(preS + (size_t)row * ND + lane * 8);
  float x[8];
#pragma unroll
  for (int i = 0; i < 8; ++i) x[i] = bf2f((unsigned short)raw[i]);
  float s = 0.f;
#pragma unroll
  for (int i = 0; i < 8; ++i) s += x[i];
#pragma unroll
  for (int o = 32; o; o >>= 1) s += __shfl_xor(s, o);
  float mu = s * (1.0f / 512.0f);
  float v = 0.f;
#pragma unroll
  for (int i = 0; i < 8; ++i) { float d = x[i] - mu; v += d * d; }
#pragma unroll
  for (int o = 32; o; o >>= 1) v += __shfl_xor(v, o);
  float rs = rsqrtf(v * (1.0f / 512.0f) + 1e-5f);
  float4 g0 = *(const float4*)(gamma + lane * 8);
  float4 g1 = *(const float4*)(gamma + lane * 8 + 4);
  float4 b0 = *(const float4*)(beta + lane * 8);
  float4 b1 = *(const float4*)(beta + lane * 8 + 4);
  float4 y0, y1;
  y0.x = (x[0] - mu) * rs * g0.x + b0.x; y0.y = (x[1] - mu) * rs * g0.y + b0.y;
  y0.z = (x[2] - mu) * rs * g0.z + b0.z; y0.w = (x[3] - mu) * rs * g0.w + b0.w;
  y1.x = (x[4] - mu) * rs * g1.x + b1.x; y1.y = (x[5] - mu) * rs * g1.y + b1.y;
  y1.z = (x[6] - mu) * rs * g1.z + b1.z; y1.w = (x[7] - mu) * rs * g1.w + b1.w;
  float* p = out + (size_t)row * ND + lane * 8;
  *(float4*)p = y0;
  *(float4*)(p + 4) = y1;
}

extern "C" void kernel_launch(void* const* d_in, const int* in_sizes, int n_in,
                              void* d_out, int out_size, void* d_ws, size_t ws_size,
                              hipStream_t stream) {
  (void)in_sizes; (void)n_in; (void)out_size; (void)ws_size;
  const int*   adj   = (const int*)d_in[0];
  const float* hid   = (const float*)d_in[1];
  const float* W     = (const float*)d_in[2];
  const float* bias  = (const float*)d_in[3];
  const float* gamma = (const float*)d_in[4];
  const float* beta  = (const float*)d_in[5];
  float* out = (float*)d_out;

  char* ws = (char*)d_ws;
  // WTcat (1 MiB, dead after k_pre) shares offset 0 with preS (written later).
  unsigned short* WTcat  = (unsigned short*)ws;                 // 1 MiB
  unsigned short* preS   = (unsigned short*)ws;                 // 16 MiB (after k_pre)
  unsigned short* Ptcat  = (unsigned short*)(ws + 16777216);    // 32 MiB
  unsigned*       packed = (unsigned*)(ws + 50331648);          // 4 MiB
  float*          invc   = (float*)(ws + 54525952);             // 128 KiB

  k_wtcat<<<dim3(8, 8, 2), 256, 0, stream>>>(W, WTcat);
  k_pack <<<1024, 256, 0, stream>>>(adj, packed, invc);
  k_pre  <<<1024, 256, 0, stream>>>(hid, WTcat, Ptcat);
  k_main <<<512, 256, 0, stream>>>(packed, Ptcat, invc, bias, hid, preS);
  k_ln   <<<4096, 256, 0, stream>>>(preS, out, gamma, beta);
}